// Round 12
// baseline (122.110 us; speedup 1.0000x reference)
//
#include <hip/hip_runtime.h>

// CoAttention, 4-kernel pipeline. R12:
//  k_prep : NEW tiny kernel — transposes all 6 weight blocks once into ws as
//           bf16 [n][k] (was re-staged+transposed 16x per block inside k_proj);
//           also does p/S init.
//  k_proj : LDS-free, zero-barrier MFMA: A-frags direct from ctx (f2bf in reg),
//           B-frags direct bf16x8 loads from pre-transposed Wt.
//  k_aff  : unchanged (R11: PAIR, 32x32 tiles, 2 blocks/CU).
//  k_final: unchanged (bf16 MFMA).

#define NEGC (-1e12f)
#define TWO_LOG2E 2.8853900817779268f
#define LOG2E 1.4426950408889634f
#define N2LOG2E (-2.8853900817779268f)

typedef __attribute__((ext_vector_type(8))) short bf16x8;
typedef __attribute__((ext_vector_type(4))) float f32x4;

__device__ __forceinline__ short f2bf(float x)   // RNE f32->bf16
{
    union { float f; unsigned u; } v; v.f = x;
    unsigned r = (v.u + 0x7FFFu + ((v.u >> 16) & 1u)) >> 16;
    return (short)r;
}

// ---------------------------------------------------------------- k_prep
// Wt[g][n][k] = W_g[k][n] as bf16, g in [0,6): {Wh1,Wh2,W12a,W12b,W21a,W21b}.
__global__ __launch_bounds__(256) void k_prep(
    const float* __restrict__ Wh, const float* __restrict__ W12,
    const float* __restrict__ W21,
    const float* __restrict__ mask1, const float* __restrict__ mask2,
    short* __restrict__ Wt,
    float* __restrict__ p1, float* __restrict__ p2,
    float* __restrict__ S1, float* __restrict__ S2)
{
    const int t = threadIdx.x, bx = blockIdx.x;
    const int g = bx >> 4, tile = bx & 15;
    const int tk = (tile >> 2) * 64, tn = (tile & 3) * 64;
    const float* Wsrc; int rbase;
    switch (g) {
      case 0:  Wsrc = Wh;  rbase = 0;   break;
      case 1:  Wsrc = Wh;  rbase = 256; break;
      case 2:  Wsrc = W12; rbase = 0;   break;
      case 3:  Wsrc = W12; rbase = 256; break;
      case 4:  Wsrc = W21; rbase = 0;   break;
      default: Wsrc = W21; rbase = 256; break;
    }

    if (bx == 0) {
        for (int idx = t; idx < 1024; idx += 256) {
            int row = idx >> 1, b = idx & 1;
            p1[b * 512 + row] = __builtin_amdgcn_exp2f(LOG2E * (1.f - mask1[idx]) * NEGC);
            p2[b * 512 + row] = __builtin_amdgcn_exp2f(LOG2E * (1.f - mask2[idx]) * NEGC);
            S1[b * 512 + row] = 0.f;
            S2[b * 512 + row] = 0.f;
        }
    }

    __shared__ __align__(16) float Ls[64 * 68];
    #pragma unroll
    for (int i = 0; i < 4; ++i) {              // 64 k-rows x 64 n, coalesced
        int slot = i * 256 + t;
        int r = slot >> 4, c4 = (slot & 15) << 2;
        *(float4*)(Ls + r * 68 + c4) =
            *(const float4*)(Wsrc + (rbase + tk + r) * 256 + tn + c4);
    }
    __syncthreads();
    #pragma unroll
    for (int i = 0; i < 4; ++i) {              // write [n][k] bf16, k-contig
        int slot = i * 256 + t;
        int n = slot >> 4, k4 = (slot & 15) << 2;
        short4 s;
        s.x = f2bf(Ls[(k4 + 0) * 68 + n]);
        s.y = f2bf(Ls[(k4 + 1) * 68 + n]);
        s.z = f2bf(Ls[(k4 + 2) * 68 + n]);
        s.w = f2bf(Ls[(k4 + 3) * 68 + n]);
        *(short4*)(Wt + g * 65536 + (tn + n) * 256 + tk + k4) = s;
    }
}

// ---------------------------------------------------------------- k_proj
// LDS-free: per wave, 16 rows x 64 cols; A-frag = ctx[row][k..k+8] (f2bf in
// reg), B-frag = Wt[n][k..k+8] direct bf16x8. No barriers -> full pipelining.
__global__ __launch_bounds__(256) void k_proj(
    const float* __restrict__ ctx1, const float* __restrict__ ctx2,
    const short* __restrict__ Wt,
    const float* __restrict__ bh, const float* __restrict__ b12,
    const float* __restrict__ b21,
    float* __restrict__ E1, float* __restrict__ E2,
    float* __restrict__ P12, float* __restrict__ U1,
    float* __restrict__ P21, float* __restrict__ U2)
{
    const int t  = threadIdx.x;
    const int g  = blockIdx.z;
    const int r0 = blockIdx.x * 64;       // rows = l*2+b in [0,1024)
    const int n0 = blockIdx.y * 64;       // N in [0,256)

    const float* A; const float* bias; int expm; float* outp;
    switch (g) {
      case 0:  A=ctx1; bias=bh;   expm=1; outp=E1;  break;
      case 1:  A=ctx2; bias=0;    expm=1; outp=E2;  break;
      case 2:  A=ctx2; bias=b12;  expm=0; outp=P12; break;
      case 3:  A=ctx1; bias=0;    expm=0; outp=U1;  break;
      case 4:  A=ctx1; bias=b21;  expm=0; outp=P21; break;
      default: A=ctx2; bias=0;    expm=0; outp=U2;  break;
    }

    const int w    = t >> 6;
    const int lane = t & 63;
    const int quad = lane >> 4;
    const int lr   = lane & 15;

    const float* ap = A + (r0 + w * 16 + lr) * 256 + quad * 8;
    const short* bp = Wt + g * 65536 + (n0 + lr) * 256 + quad * 8;

    f32x4 acc[4] = {};
    #pragma unroll
    for (int kc = 0; kc < 256; kc += 32) {
        float4 v0 = *(const float4*)(ap + kc);
        float4 v1 = *(const float4*)(ap + kc + 4);
        bf16x8 a;
        a[0] = f2bf(v0.x); a[1] = f2bf(v0.y); a[2] = f2bf(v0.z); a[3] = f2bf(v0.w);
        a[4] = f2bf(v1.x); a[5] = f2bf(v1.y); a[6] = f2bf(v1.z); a[7] = f2bf(v1.w);
        #pragma unroll
        for (int nc = 0; nc < 4; ++nc) {
            bf16x8 b = *(const bf16x8*)(bp + nc * 4096 + kc);
            acc[nc] = __builtin_amdgcn_mfma_f32_16x16x32_bf16(a, b, acc[nc], 0, 0, 0);
        }
    }

    #pragma unroll
    for (int nc = 0; nc < 4; ++nc) {
        const int col = n0 + nc * 16 + lr;
        const float bv = bias ? bias[col] : 0.f;
        #pragma unroll
        for (int reg = 0; reg < 4; ++reg) {
            int row  = r0 + w * 16 + quad * 4 + reg;   // = l*2+b
            int orow = ((row & 1) << 9) + (row >> 1);
            float v = acc[nc][reg] + bv;
            if (expm) v = __builtin_amdgcn_exp2f(v * TWO_LOG2E);
            outp[orow * 256 + col] = v;
        }
    }
}

// ---------------------------------------------------------------- k_aff
// PAIR: acc += w.x/x0 + w.y/x1 + w.z/x2 + w.w/x3 with 2 rcp via pairing.
#define PAIR(AV, QV, WV, ACC) do {                                    \
    float x0_ = fmaf(AV.x, QV.x, 1.f);                                \
    float x1_ = fmaf(AV.y, QV.y, 1.f);                                \
    float x2_ = fmaf(AV.z, QV.z, 1.f);                                \
    float x3_ = fmaf(AV.w, QV.w, 1.f);                                \
    float r01_ = __builtin_amdgcn_rcpf(x0_ * x1_);                    \
    float r23_ = __builtin_amdgcn_rcpf(x2_ * x3_);                    \
    float z01_ = fmaf(WV.y, x0_, WV.x * x1_);                         \
    float z23_ = fmaf(WV.w, x2_, WV.z * x3_);                         \
    ACC = fmaf(r01_, z01_, ACC);                                      \
    ACC = fmaf(r23_, z23_, ACC);                                      \
} while (0)

__global__ __launch_bounds__(256) void k_aff(
    const float* __restrict__ E1g, const float* __restrict__ E2g,
    const float* __restrict__ wo,
    const float* __restrict__ p1g, const float* __restrict__ p2g,
    float* __restrict__ EN, float* __restrict__ ET,
    float* __restrict__ S1, float* __restrict__ S2)
{
    const int t  = threadIdx.x;
    const int l0 = blockIdx.x * 32, m0 = blockIdx.y * 32, b = blockIdx.z;

    __shared__ __align__(16) float E1s[32 * 132];
    __shared__ __align__(16) float E2s[32 * 132];
    __shared__ __align__(16) float affs[32 * 36];

    const int tl = t >> 4, tm = t & 15;   // cells: l in {tl,tl+16}, m in {tm,tm+16}
    float acc[2][2] = {};

    for (int kc = 0; kc < 256; kc += 128) {
        #pragma unroll
        for (int i = 0; i < 4; ++i) {               // 32 rows x 128 k, both panels
            int slot = i * 256 + t;
            int r = slot >> 5, kq = (slot & 31) << 2;
            *(float4*)(E1s + r * 132 + kq) =
                *(const float4*)(E1g + (((b << 9) + l0 + r) << 8) + kc + kq);
            *(float4*)(E2s + r * 132 + kq) =
                *(const float4*)(E2g + (((b << 9) + m0 + r) << 8) + kc + kq);
        }
        __syncthreads();
        #pragma unroll 4
        for (int k0 = 0; k0 < 128; k0 += 4) {
            const float4 w  = *(const float4*)(wo + kc + k0);   // uniform -> s_load
            const float4 a0 = *(const float4*)(E1s + tl * 132 + k0);
            const float4 a1 = *(const float4*)(E1s + (tl + 16) * 132 + k0);
            const float4 q0 = *(const float4*)(E2s + tm * 132 + k0);
            const float4 q1 = *(const float4*)(E2s + (tm + 16) * 132 + k0);
            PAIR(a0, q0, w, acc[0][0]);
            PAIR(a0, q1, w, acc[0][1]);
            PAIR(a1, q0, w, acc[1][0]);
            PAIR(a1, q1, w, acc[1][1]);
        }
        __syncthreads();
    }

    affs[tl * 36 + tm]             = __builtin_amdgcn_exp2f(acc[0][0] * N2LOG2E);
    affs[tl * 36 + tm + 16]        = __builtin_amdgcn_exp2f(acc[0][1] * N2LOG2E);
    affs[(tl + 16) * 36 + tm]      = __builtin_amdgcn_exp2f(acc[1][0] * N2LOG2E);
    affs[(tl + 16) * 36 + tm + 16] = __builtin_amdgcn_exp2f(acc[1][1] * N2LOG2E);
    __syncthreads();

    const int r  = t >> 3;
    const int c4 = (t & 7) << 2;
    // natural (32 l-rows x 32 m-cols): EN[l][m]=E*p1[l]; S1[l]+=sum_m E*p2[m]
    {
        float4 e = *(const float4*)(affs + r * 36 + c4);
        const float p1r = p1g[(b << 9) + l0 + r];
        float4 vn = make_float4(e.x * p1r, e.y * p1r, e.z * p1r, e.w * p1r);
        *(float4*)(EN + (((b << 9) + l0 + r) << 9) + m0 + c4) = vn;
        float4 p2v = *(const float4*)(p2g + (b << 9) + m0 + c4);
        float s = (e.x * p2v.x + e.y * p2v.y) + (e.z * p2v.z + e.w * p2v.w);
        s += __shfl_xor(s, 1, 64);
        s += __shfl_xor(s, 2, 64);
        s += __shfl_xor(s, 4, 64);
        if ((t & 7) == 0) atomicAdd(S1 + (b << 9) + l0 + r, s);
    }
    // transposed (32 m-rows x 32 l-cols): ET[m][l]=E^T*p2[m]; S2[m]+=sum_l E*p1[l]
    {
        float4 te;
        te.x = affs[(c4 + 0) * 36 + r];
        te.y = affs[(c4 + 1) * 36 + r];
        te.z = affs[(c4 + 2) * 36 + r];
        te.w = affs[(c4 + 3) * 36 + r];
        const float p2r = p2g[(b << 9) + m0 + r];
        float4 vt = make_float4(te.x * p2r, te.y * p2r, te.z * p2r, te.w * p2r);
        *(float4*)(ET + (((b << 9) + m0 + r) << 9) + l0 + c4) = vt;
        float4 p1v = *(const float4*)(p1g + (b << 9) + l0 + c4);
        float s = (te.x * p1v.x + te.y * p1v.y) + (te.z * p1v.z + te.w * p1v.w);
        s += __shfl_xor(s, 1, 64);
        s += __shfl_xor(s, 2, 64);
        s += __shfl_xor(s, 4, 64);
        if ((t & 7) == 0) atomicAdd(S2 + (b << 9) + m0 + r, s);
    }
}

// --------------------------------------------------------------- k_final
__global__ __launch_bounds__(256) void k_final(
    const float* __restrict__ EN, const float* __restrict__ ET,
    const float* __restrict__ U1, const float* __restrict__ U2,
    const float* __restrict__ P12, const float* __restrict__ P21,
    const float* __restrict__ S1, const float* __restrict__ S2,
    float* __restrict__ out)
{
    const int t   = threadIdx.x;
    const int r0  = blockIdx.x * 32, n0 = blockIdx.y * 32;
    const int dir = blockIdx.z >> 1, b = blockIdx.z & 1;
    const float* Ag = (dir == 0 ? ET  : EN)  + b * 262144;  // [row][k], stride 512
    const float* Sg = (dir == 0 ? S1  : S2)  + b * 512;
    const float* Bg = (dir == 0 ? U1  : U2)  + b * 131072;  // [k][n], stride 256
    const float* Pg = (dir == 0 ? P12 : P21) + b * 131072;  // [row][n], stride 256
    float* o = out + (dir == 0 ? 262144 : 0);

    __shared__ __align__(16) short Abf[32 * 72];    // [row][k] bf16, rs folded
    __shared__ __align__(16) short Bbf[32 * 72];    // [n][k] bf16 (U^T)
    __shared__ __align__(16) float rs[512];

    for (int i = t; i < 512; i += 256)
        rs[i] = __builtin_amdgcn_rcpf(Sg[i]);
    __syncthreads();

    const int w    = t >> 6;
    const int lane = t & 63;
    const int quad = lane >> 4;
    const int lr   = lane & 15;
    const int wr   = (w >> 1) << 4, wc = (w & 1) << 4;
    f32x4 acc = {};

    for (int kc = 0; kc < 512; kc += 64) {
        #pragma unroll
        for (int i = 0; i < 2; ++i) {               // A: 32 rows x 64 k, rs-scaled
            int slot = i * 256 + t;
            int r = slot >> 4, kq = (slot & 15) << 2;
            float4 v = *(const float4*)(Ag + ((r0 + r) << 9) + kc + kq);
            const float* rp = rs + kc + kq;
            short4 s;
            s.x = f2bf(v.x * rp[0]); s.y = f2bf(v.y * rp[1]);
            s.z = f2bf(v.z * rp[2]); s.w = f2bf(v.w * rp[3]);
            *(short4*)(Abf + r * 72 + kq) = s;
        }
        #pragma unroll
        for (int i = 0; i < 2; ++i) {               // B: 64 k x 32 n -> [n][k]
            int slot = i * 256 + t;
            int bk = slot >> 3, bn4 = (slot & 7) << 2;
            float4 v = *(const float4*)(Bg + ((kc + bk) << 8) + n0 + bn4);
            Bbf[(bn4 + 0) * 72 + bk] = f2bf(v.x);
            Bbf[(bn4 + 1) * 72 + bk] = f2bf(v.y);
            Bbf[(bn4 + 2) * 72 + bk] = f2bf(v.z);
            Bbf[(bn4 + 3) * 72 + bk] = f2bf(v.w);
        }
        __syncthreads();
        #pragma unroll
        for (int s = 0; s < 2; ++s) {
            const int kb = s * 32 + quad * 8;
            bf16x8 a = *(const bf16x8*)(Abf + (wr + lr) * 72 + kb);
            bf16x8 bb = *(const bf16x8*)(Bbf + (wc + lr) * 72 + kb);
            acc = __builtin_amdgcn_mfma_f32_16x16x32_bf16(a, bb, acc, 0, 0, 0);
        }
        __syncthreads();
    }

    const int col = n0 + wc + lr;
    #pragma unroll
    for (int reg = 0; reg < 4; ++reg) {
        const int m = r0 + wr + quad * 4 + reg;
        float v = acc[reg] + Pg[(m << 8) + col];
        float tv = 1.f - 2.f * __builtin_amdgcn_rcpf(
                       __builtin_amdgcn_exp2f(v * TWO_LOG2E) + 1.f);
        o[((m << 1) + b) * 256 + col] = tv;
    }
}

// ---------------------------------------------------------------- launch
extern "C" void kernel_launch(void* const* d_in, const int* in_sizes, int n_in,
                              void* d_out, int out_size, void* d_ws, size_t ws_size,
                              hipStream_t stream)
{
    const float* ctx1 = (const float*)d_in[0];
    const float* ctx2 = (const float*)d_in[1];
    const float* m1   = (const float*)d_in[2];
    const float* m2   = (const float*)d_in[3];
    const float* Wh   = (const float*)d_in[4];
    const float* bh   = (const float*)d_in[5];
    const float* wo   = (const float*)d_in[6];
    const float* W12  = (const float*)d_in[7];
    const float* b12  = (const float*)d_in[8];
    const float* W21  = (const float*)d_in[9];
    const float* b21  = (const float*)d_in[10];
    float* out = (float*)d_out;
    float* ws  = (float*)d_ws;

    float* E1  = ws;                 // 262144
    float* E2  = E1  + 262144;
    float* P12 = E2  + 262144;
    float* U1  = P12 + 262144;
    float* P21 = U1  + 262144;
    float* U2  = P21 + 262144;
    float* p1  = U2  + 262144;       // 1024
    float* p2  = p1  + 1024;
    float* S1  = p2  + 1024;         // 1024
    float* S2  = S1  + 1024;
    float* EN  = S2  + 1024;         // 524288
    float* ET  = EN  + 524288;       // 524288
    short* Wt  = (short*)(ET + 524288);  // 6*65536 bf16 = 768 KB

    hipLaunchKernelGGL(k_prep, dim3(96), dim3(256), 0, stream,
                       Wh, W12, W21, m1, m2, Wt, p1, p2, S1, S2);
    hipLaunchKernelGGL(k_proj, dim3(16, 4, 6), dim3(256), 0, stream,
                       ctx1, ctx2, Wt, bh, b12, b21,
                       E1, E2, P12, U1, P21, U2);
    hipLaunchKernelGGL(k_aff, dim3(16, 16, 2), dim3(256), 0, stream,
                       E1, E2, wo, p1, p2, EN, ET, S1, S2);
    hipLaunchKernelGGL(k_final, dim3(16, 8, 4), dim3(256), 0, stream,
                       EN, ET, U1, U2, P12, P21, S1, S2, out);
}

// Round 13
// 119.371 us; speedup vs baseline: 1.0229x; 1.0229x over previous
//
#include <hip/hip_runtime.h>

// CoAttention, 3-kernel pipeline. R13 = R11 + ONE change in k_aff:
//  k_proj : identical to R11 (both R10/R12 restructures regressed; this shape
//           is a measured local optimum).
//  k_aff  : E1 panel no longer staged in LDS — a0/a1 read direct from global
//           (16 lanes share each address -> 4 coalesced 16B transactions per
//           wave-iter, L2-resident). LDS reads/iter 5 -> 2 (12.8us -> ~5us
//           port time). E2 panel + PAIR + epilogue unchanged.
//  k_final: identical to R11.

#define NEGC (-1e12f)
#define TWO_LOG2E 2.8853900817779268f
#define LOG2E 1.4426950408889634f
#define N2LOG2E (-2.8853900817779268f)

typedef __attribute__((ext_vector_type(8))) short bf16x8;
typedef __attribute__((ext_vector_type(4))) float f32x4;

__device__ __forceinline__ short f2bf(float x)   // RNE f32->bf16
{
    union { float f; unsigned u; } v; v.f = x;
    unsigned r = (v.u + 0x7FFFu + ((v.u >> 16) & 1u)) >> 16;
    return (short)r;
}

// ---------------------------------------------------------------- k_proj
__global__ __launch_bounds__(256) void k_proj(
    const float* __restrict__ ctx1, const float* __restrict__ ctx2,
    const float* __restrict__ Wh, const float* __restrict__ bh,
    const float* __restrict__ W12, const float* __restrict__ b12,
    const float* __restrict__ W21, const float* __restrict__ b21,
    const float* __restrict__ mask1, const float* __restrict__ mask2,
    float* __restrict__ E1, float* __restrict__ E2,
    float* __restrict__ P12, float* __restrict__ U1,
    float* __restrict__ P21, float* __restrict__ U2,
    float* __restrict__ p1, float* __restrict__ p2,
    float* __restrict__ S1, float* __restrict__ S2)
{
    const int t  = threadIdx.x;
    const int g  = blockIdx.z;
    const int r0 = blockIdx.x * 64;       // rows = l*2+b in [0,1024)
    const int n0 = blockIdx.y * 64;       // N in [0,256)

    const float* A; const float* W; const float* bias; int expm; float* outp;
    switch (g) {
      case 0:  A=ctx1; W=Wh;        bias=bh;   expm=1; outp=E1;  break;
      case 1:  A=ctx2; W=Wh+65536;  bias=0;    expm=1; outp=E2;  break;
      case 2:  A=ctx2; W=W12;       bias=b12;  expm=0; outp=P12; break;
      case 3:  A=ctx1; W=W12+65536; bias=0;    expm=0; outp=U1;  break;
      case 4:  A=ctx1; W=W21;       bias=b21;  expm=0; outp=P21; break;
      default: A=ctx2; W=W21+65536; bias=0;    expm=0; outp=U2;  break;
    }

    if (g == 0 && blockIdx.x == 0 && blockIdx.y == 0) {
        for (int idx = t; idx < 1024; idx += 256) {
            int row = idx >> 1, b = idx & 1;
            p1[b * 512 + row] = __builtin_amdgcn_exp2f(LOG2E * (1.f - mask1[idx]) * NEGC);
            p2[b * 512 + row] = __builtin_amdgcn_exp2f(LOG2E * (1.f - mask2[idx]) * NEGC);
            S1[b * 512 + row] = 0.f;
            S2[b * 512 + row] = 0.f;
        }
    }

    __shared__ __align__(16) short Abf[64 * 136];   // [m][k] bf16
    __shared__ __align__(16) short Bbf[64 * 136];   // [n][k] bf16 (W^T)

    const int w    = t >> 6;
    const int lane = t & 63;
    const int quad = lane >> 4;
    const int lr   = lane & 15;

    f32x4 acc[4] = {};

    for (int kc = 0; kc < 256; kc += 128) {
        #pragma unroll
        for (int i = 0; i < 8; ++i) {                 // A: 64 rows x 128 k
            int slot = i * 256 + t;
            int r = slot >> 5, kq = (slot & 31) << 2;
            float4 v = *(const float4*)(A + (r0 + r) * 256 + kc + kq);
            short4 s; s.x = f2bf(v.x); s.y = f2bf(v.y); s.z = f2bf(v.z); s.w = f2bf(v.w);
            *(short4*)(Abf + r * 136 + kq) = s;
        }
        #pragma unroll
        for (int i = 0; i < 8; ++i) {                 // B: 128 k x 64 n -> B^T
            int slot = i * 256 + t;
            int bk = slot >> 4, bn4 = (slot & 15) << 2;
            float4 v = *(const float4*)(W + (kc + bk) * 256 + n0 + bn4);
            Bbf[(bn4 + 0) * 136 + bk] = f2bf(v.x);
            Bbf[(bn4 + 1) * 136 + bk] = f2bf(v.y);
            Bbf[(bn4 + 2) * 136 + bk] = f2bf(v.z);
            Bbf[(bn4 + 3) * 136 + bk] = f2bf(v.w);
        }
        __syncthreads();
        #pragma unroll
        for (int s = 0; s < 4; ++s) {
            const int kb = s * 32 + quad * 8;
            bf16x8 a = *(const bf16x8*)(Abf + (w * 16 + lr) * 136 + kb);
            #pragma unroll
            for (int nc = 0; nc < 4; ++nc) {
                bf16x8 b = *(const bf16x8*)(Bbf + (nc * 16 + lr) * 136 + kb);
                acc[nc] = __builtin_amdgcn_mfma_f32_16x16x32_bf16(a, b, acc[nc], 0, 0, 0);
            }
        }
        __syncthreads();
    }

    #pragma unroll
    for (int nc = 0; nc < 4; ++nc) {
        const int col = n0 + nc * 16 + lr;
        const float bv = bias ? bias[col] : 0.f;
        #pragma unroll
        for (int reg = 0; reg < 4; ++reg) {
            int row  = r0 + w * 16 + quad * 4 + reg;   // = l*2+b
            int orow = ((row & 1) << 9) + (row >> 1);
            float v = acc[nc][reg] + bv;
            if (expm) v = __builtin_amdgcn_exp2f(v * TWO_LOG2E);
            outp[orow * 256 + col] = v;
        }
    }
}

// ---------------------------------------------------------------- k_aff
// PAIR: acc += w.x/x0 + w.y/x1 + w.z/x2 + w.w/x3 with 2 rcp via pairing.
#define PAIR(AV, QV, WV, ACC) do {                                    \
    float x0_ = fmaf(AV.x, QV.x, 1.f);                                \
    float x1_ = fmaf(AV.y, QV.y, 1.f);                                \
    float x2_ = fmaf(AV.z, QV.z, 1.f);                                \
    float x3_ = fmaf(AV.w, QV.w, 1.f);                                \
    float r01_ = __builtin_amdgcn_rcpf(x0_ * x1_);                    \
    float r23_ = __builtin_amdgcn_rcpf(x2_ * x3_);                    \
    float z01_ = fmaf(WV.y, x0_, WV.x * x1_);                         \
    float z23_ = fmaf(WV.w, x2_, WV.z * x3_);                         \
    ACC = fmaf(r01_, z01_, ACC);                                      \
    ACC = fmaf(r23_, z23_, ACC);                                      \
} while (0)

__global__ __launch_bounds__(256) void k_aff(
    const float* __restrict__ E1g, const float* __restrict__ E2g,
    const float* __restrict__ wo,
    const float* __restrict__ p1g, const float* __restrict__ p2g,
    float* __restrict__ EN, float* __restrict__ ET,
    float* __restrict__ S1, float* __restrict__ S2)
{
    const int t  = threadIdx.x;
    const int l0 = blockIdx.x * 32, m0 = blockIdx.y * 32, b = blockIdx.z;

    __shared__ __align__(16) float E2s[32 * 132];   // 16.9 KB (E1 read direct)
    __shared__ __align__(16) float affs[32 * 36];   //  4.6 KB

    const int tl = t >> 4, tm = t & 15;   // cells: l in {tl,tl+16}, m in {tm,tm+16}
    // E1 rows read direct from global: 16 lanes share each address ->
    // 4 coalesced 16B transactions per wave-iter, L2-resident.
    const float* e1a = E1g + (((b << 9) + l0 + tl) << 8);
    const float* e1b = E1g + (((b << 9) + l0 + tl + 16) << 8);
    float acc[2][2] = {};

    for (int kc = 0; kc < 256; kc += 128) {
        #pragma unroll
        for (int i = 0; i < 4; ++i) {               // E2: 32 rows x 128 k
            int slot = i * 256 + t;
            int r = slot >> 5, kq = (slot & 31) << 2;
            *(float4*)(E2s + r * 132 + kq) =
                *(const float4*)(E2g + (((b << 9) + m0 + r) << 8) + kc + kq);
        }
        __syncthreads();
        #pragma unroll 4
        for (int k0 = 0; k0 < 128; k0 += 4) {
            const float4 w  = *(const float4*)(wo + kc + k0);   // uniform -> s_load
            const float4 a0 = *(const float4*)(e1a + kc + k0);  // global direct
            const float4 a1 = *(const float4*)(e1b + kc + k0);
            const float4 q0 = *(const float4*)(E2s + tm * 132 + k0);
            const float4 q1 = *(const float4*)(E2s + (tm + 16) * 132 + k0);
            PAIR(a0, q0, w, acc[0][0]);
            PAIR(a0, q1, w, acc[0][1]);
            PAIR(a1, q0, w, acc[1][0]);
            PAIR(a1, q1, w, acc[1][1]);
        }
        __syncthreads();
    }

    affs[tl * 36 + tm]             = __builtin_amdgcn_exp2f(acc[0][0] * N2LOG2E);
    affs[tl * 36 + tm + 16]        = __builtin_amdgcn_exp2f(acc[0][1] * N2LOG2E);
    affs[(tl + 16) * 36 + tm]      = __builtin_amdgcn_exp2f(acc[1][0] * N2LOG2E);
    affs[(tl + 16) * 36 + tm + 16] = __builtin_amdgcn_exp2f(acc[1][1] * N2LOG2E);
    __syncthreads();

    const int r  = t >> 3;
    const int c4 = (t & 7) << 2;
    // natural (32 l-rows x 32 m-cols): EN[l][m]=E*p1[l]; S1[l]+=sum_m E*p2[m]
    {
        float4 e = *(const float4*)(affs + r * 36 + c4);
        const float p1r = p1g[(b << 9) + l0 + r];
        float4 vn = make_float4(e.x * p1r, e.y * p1r, e.z * p1r, e.w * p1r);
        *(float4*)(EN + (((b << 9) + l0 + r) << 9) + m0 + c4) = vn;
        float4 p2v = *(const float4*)(p2g + (b << 9) + m0 + c4);
        float s = (e.x * p2v.x + e.y * p2v.y) + (e.z * p2v.z + e.w * p2v.w);
        s += __shfl_xor(s, 1, 64);
        s += __shfl_xor(s, 2, 64);
        s += __shfl_xor(s, 4, 64);
        if ((t & 7) == 0) atomicAdd(S1 + (b << 9) + l0 + r, s);
    }
    // transposed (32 m-rows x 32 l-cols): ET[m][l]=E^T*p2[m]; S2[m]+=sum_l E*p1[l]
    {
        float4 te;
        te.x = affs[(c4 + 0) * 36 + r];
        te.y = affs[(c4 + 1) * 36 + r];
        te.z = affs[(c4 + 2) * 36 + r];
        te.w = affs[(c4 + 3) * 36 + r];
        const float p2r = p2g[(b << 9) + m0 + r];
        float4 vt = make_float4(te.x * p2r, te.y * p2r, te.z * p2r, te.w * p2r);
        *(float4*)(ET + (((b << 9) + m0 + r) << 9) + l0 + c4) = vt;
        float4 p1v = *(const float4*)(p1g + (b << 9) + l0 + c4);
        float s = (te.x * p1v.x + te.y * p1v.y) + (te.z * p1v.z + te.w * p1v.w);
        s += __shfl_xor(s, 1, 64);
        s += __shfl_xor(s, 2, 64);
        s += __shfl_xor(s, 4, 64);
        if ((t & 7) == 0) atomicAdd(S2 + (b << 9) + m0 + r, s);
    }
}

// --------------------------------------------------------------- k_final
__global__ __launch_bounds__(256) void k_final(
    const float* __restrict__ EN, const float* __restrict__ ET,
    const float* __restrict__ U1, const float* __restrict__ U2,
    const float* __restrict__ P12, const float* __restrict__ P21,
    const float* __restrict__ S1, const float* __restrict__ S2,
    float* __restrict__ out)
{
    const int t   = threadIdx.x;
    const int r0  = blockIdx.x * 32, n0 = blockIdx.y * 32;
    const int dir = blockIdx.z >> 1, b = blockIdx.z & 1;
    const float* Ag = (dir == 0 ? ET  : EN)  + b * 262144;  // [row][k], stride 512
    const float* Sg = (dir == 0 ? S1  : S2)  + b * 512;
    const float* Bg = (dir == 0 ? U1  : U2)  + b * 131072;  // [k][n], stride 256
    const float* Pg = (dir == 0 ? P12 : P21) + b * 131072;  // [row][n], stride 256
    float* o = out + (dir == 0 ? 262144 : 0);

    __shared__ __align__(16) short Abf[32 * 72];    // [row][k] bf16, rs folded
    __shared__ __align__(16) short Bbf[32 * 72];    // [n][k] bf16 (U^T)
    __shared__ __align__(16) float rs[512];

    for (int i = t; i < 512; i += 256)
        rs[i] = __builtin_amdgcn_rcpf(Sg[i]);
    __syncthreads();

    const int w    = t >> 6;
    const int lane = t & 63;
    const int quad = lane >> 4;
    const int lr   = lane & 15;
    const int wr   = (w >> 1) << 4, wc = (w & 1) << 4;
    f32x4 acc = {};

    for (int kc = 0; kc < 512; kc += 64) {
        #pragma unroll
        for (int i = 0; i < 2; ++i) {               // A: 32 rows x 64 k, rs-scaled
            int slot = i * 256 + t;
            int r = slot >> 4, kq = (slot & 15) << 2;
            float4 v = *(const float4*)(Ag + ((r0 + r) << 9) + kc + kq);
            const float* rp = rs + kc + kq;
            short4 s;
            s.x = f2bf(v.x * rp[0]); s.y = f2bf(v.y * rp[1]);
            s.z = f2bf(v.z * rp[2]); s.w = f2bf(v.w * rp[3]);
            *(short4*)(Abf + r * 72 + kq) = s;
        }
        #pragma unroll
        for (int i = 0; i < 2; ++i) {               // B: 64 k x 32 n -> [n][k]
            int slot = i * 256 + t;
            int bk = slot >> 3, bn4 = (slot & 7) << 2;
            float4 v = *(const float4*)(Bg + ((kc + bk) << 8) + n0 + bn4);
            Bbf[(bn4 + 0) * 72 + bk] = f2bf(v.x);
            Bbf[(bn4 + 1) * 72 + bk] = f2bf(v.y);
            Bbf[(bn4 + 2) * 72 + bk] = f2bf(v.z);
            Bbf[(bn4 + 3) * 72 + bk] = f2bf(v.w);
        }
        __syncthreads();
        #pragma unroll
        for (int s = 0; s < 2; ++s) {
            const int kb = s * 32 + quad * 8;
            bf16x8 a = *(const bf16x8*)(Abf + (wr + lr) * 72 + kb);
            bf16x8 bb = *(const bf16x8*)(Bbf + (wc + lr) * 72 + kb);
            acc = __builtin_amdgcn_mfma_f32_16x16x32_bf16(a, bb, acc, 0, 0, 0);
        }
        __syncthreads();
    }

    const int col = n0 + wc + lr;
    #pragma unroll
    for (int reg = 0; reg < 4; ++reg) {
        const int m = r0 + wr + quad * 4 + reg;
        float v = acc[reg] + Pg[(m << 8) + col];
        float tv = 1.f - 2.f * __builtin_amdgcn_rcpf(
                       __builtin_amdgcn_exp2f(v * TWO_LOG2E) + 1.f);
        o[((m << 1) + b) * 256 + col] = tv;
    }
}

// ---------------------------------------------------------------- launch
extern "C" void kernel_launch(void* const* d_in, const int* in_sizes, int n_in,
                              void* d_out, int out_size, void* d_ws, size_t ws_size,
                              hipStream_t stream)
{
    const float* ctx1 = (const float*)d_in[0];
    const float* ctx2 = (const float*)d_in[1];
    const float* m1   = (const float*)d_in[2];
    const float* m2   = (const float*)d_in[3];
    const float* Wh   = (const float*)d_in[4];
    const float* bh   = (const float*)d_in[5];
    const float* wo   = (const float*)d_in[6];
    const float* W12  = (const float*)d_in[7];
    const float* b12  = (const float*)d_in[8];
    const float* W21  = (const float*)d_in[9];
    const float* b21  = (const float*)d_in[10];
    float* out = (float*)d_out;
    float* ws  = (float*)d_ws;

    float* E1  = ws;                 // 262144
    float* E2  = E1  + 262144;
    float* P12 = E2  + 262144;
    float* U1  = P12 + 262144;
    float* P21 = U1  + 262144;
    float* U2  = P21 + 262144;
    float* p1  = U2  + 262144;       // 1024
    float* p2  = p1  + 1024;
    float* S1  = p2  + 1024;         // 1024
    float* S2  = S1  + 1024;
    float* EN  = S2  + 1024;         // 524288
    float* ET  = EN  + 524288;       // 524288

    hipLaunchKernelGGL(k_proj, dim3(16, 4, 6), dim3(256), 0, stream,
                       ctx1, ctx2, Wh, bh, W12, b12, W21, b21, m1, m2,
                       E1, E2, P12, U1, P21, U2, p1, p2, S1, S2);
    hipLaunchKernelGGL(k_aff, dim3(16, 16, 2), dim3(256), 0, stream,
                       E1, E2, wo, p1, p2, EN, ET, S1, S2);
    hipLaunchKernelGGL(k_final, dim3(16, 8, 4), dim3(256), 0, stream,
                       EN, ET, U1, U2, P12, P21, S1, S2, out);
}

// Round 14
// 119.059 us; speedup vs baseline: 1.0256x; 1.0026x over previous
//
#include <hip/hip_runtime.h>

// CoAttention, 3-kernel pipeline. R14:
//  k_proj : identical to R11/R13 (measured local optimum).
//  k_aff  : identical compute (R13: E1 direct, PAIR); epilogue now stores
//           EN/ET as bf16 (half write bytes; enables k_final A-direct).
//  k_final: restructured — A-frags read DIRECT from global bf16 (contiguous,
//           no conversion, no LDS); rs normalization folded into B side
//           (sum_k ET[m][k]*rs[k]*U[k][n]); B staged ONCE for K=512 with rs
//           folded -> 2 barriers total (was 16), ~10x fewer LDS ops.

#define NEGC (-1e12f)
#define TWO_LOG2E 2.8853900817779268f
#define LOG2E 1.4426950408889634f
#define N2LOG2E (-2.8853900817779268f)

typedef __attribute__((ext_vector_type(8))) short bf16x8;
typedef __attribute__((ext_vector_type(4))) float f32x4;

__device__ __forceinline__ short f2bf(float x)   // RNE f32->bf16
{
    union { float f; unsigned u; } v; v.f = x;
    unsigned r = (v.u + 0x7FFFu + ((v.u >> 16) & 1u)) >> 16;
    return (short)r;
}

// ---------------------------------------------------------------- k_proj
__global__ __launch_bounds__(256) void k_proj(
    const float* __restrict__ ctx1, const float* __restrict__ ctx2,
    const float* __restrict__ Wh, const float* __restrict__ bh,
    const float* __restrict__ W12, const float* __restrict__ b12,
    const float* __restrict__ W21, const float* __restrict__ b21,
    const float* __restrict__ mask1, const float* __restrict__ mask2,
    float* __restrict__ E1, float* __restrict__ E2,
    float* __restrict__ P12, float* __restrict__ U1,
    float* __restrict__ P21, float* __restrict__ U2,
    float* __restrict__ p1, float* __restrict__ p2,
    float* __restrict__ S1, float* __restrict__ S2)
{
    const int t  = threadIdx.x;
    const int g  = blockIdx.z;
    const int r0 = blockIdx.x * 64;       // rows = l*2+b in [0,1024)
    const int n0 = blockIdx.y * 64;       // N in [0,256)

    const float* A; const float* W; const float* bias; int expm; float* outp;
    switch (g) {
      case 0:  A=ctx1; W=Wh;        bias=bh;   expm=1; outp=E1;  break;
      case 1:  A=ctx2; W=Wh+65536;  bias=0;    expm=1; outp=E2;  break;
      case 2:  A=ctx2; W=W12;       bias=b12;  expm=0; outp=P12; break;
      case 3:  A=ctx1; W=W12+65536; bias=0;    expm=0; outp=U1;  break;
      case 4:  A=ctx1; W=W21;       bias=b21;  expm=0; outp=P21; break;
      default: A=ctx2; W=W21+65536; bias=0;    expm=0; outp=U2;  break;
    }

    if (g == 0 && blockIdx.x == 0 && blockIdx.y == 0) {
        for (int idx = t; idx < 1024; idx += 256) {
            int row = idx >> 1, b = idx & 1;
            p1[b * 512 + row] = __builtin_amdgcn_exp2f(LOG2E * (1.f - mask1[idx]) * NEGC);
            p2[b * 512 + row] = __builtin_amdgcn_exp2f(LOG2E * (1.f - mask2[idx]) * NEGC);
            S1[b * 512 + row] = 0.f;
            S2[b * 512 + row] = 0.f;
        }
    }

    __shared__ __align__(16) short Abf[64 * 136];   // [m][k] bf16
    __shared__ __align__(16) short Bbf[64 * 136];   // [n][k] bf16 (W^T)

    const int w    = t >> 6;
    const int lane = t & 63;
    const int quad = lane >> 4;
    const int lr   = lane & 15;

    f32x4 acc[4] = {};

    for (int kc = 0; kc < 256; kc += 128) {
        #pragma unroll
        for (int i = 0; i < 8; ++i) {                 // A: 64 rows x 128 k
            int slot = i * 256 + t;
            int r = slot >> 5, kq = (slot & 31) << 2;
            float4 v = *(const float4*)(A + (r0 + r) * 256 + kc + kq);
            short4 s; s.x = f2bf(v.x); s.y = f2bf(v.y); s.z = f2bf(v.z); s.w = f2bf(v.w);
            *(short4*)(Abf + r * 136 + kq) = s;
        }
        #pragma unroll
        for (int i = 0; i < 8; ++i) {                 // B: 128 k x 64 n -> B^T
            int slot = i * 256 + t;
            int bk = slot >> 4, bn4 = (slot & 15) << 2;
            float4 v = *(const float4*)(W + (kc + bk) * 256 + n0 + bn4);
            Bbf[(bn4 + 0) * 136 + bk] = f2bf(v.x);
            Bbf[(bn4 + 1) * 136 + bk] = f2bf(v.y);
            Bbf[(bn4 + 2) * 136 + bk] = f2bf(v.z);
            Bbf[(bn4 + 3) * 136 + bk] = f2bf(v.w);
        }
        __syncthreads();
        #pragma unroll
        for (int s = 0; s < 4; ++s) {
            const int kb = s * 32 + quad * 8;
            bf16x8 a = *(const bf16x8*)(Abf + (w * 16 + lr) * 136 + kb);
            #pragma unroll
            for (int nc = 0; nc < 4; ++nc) {
                bf16x8 b = *(const bf16x8*)(Bbf + (nc * 16 + lr) * 136 + kb);
                acc[nc] = __builtin_amdgcn_mfma_f32_16x16x32_bf16(a, b, acc[nc], 0, 0, 0);
            }
        }
        __syncthreads();
    }

    #pragma unroll
    for (int nc = 0; nc < 4; ++nc) {
        const int col = n0 + nc * 16 + lr;
        const float bv = bias ? bias[col] : 0.f;
        #pragma unroll
        for (int reg = 0; reg < 4; ++reg) {
            int row  = r0 + w * 16 + quad * 4 + reg;   // = l*2+b
            int orow = ((row & 1) << 9) + (row >> 1);
            float v = acc[nc][reg] + bv;
            if (expm) v = __builtin_amdgcn_exp2f(v * TWO_LOG2E);
            outp[orow * 256 + col] = v;
        }
    }
}

// ---------------------------------------------------------------- k_aff
// PAIR: acc += w.x/x0 + w.y/x1 + w.z/x2 + w.w/x3 with 2 rcp via pairing.
#define PAIR(AV, QV, WV, ACC) do {                                    \
    float x0_ = fmaf(AV.x, QV.x, 1.f);                                \
    float x1_ = fmaf(AV.y, QV.y, 1.f);                                \
    float x2_ = fmaf(AV.z, QV.z, 1.f);                                \
    float x3_ = fmaf(AV.w, QV.w, 1.f);                                \
    float r01_ = __builtin_amdgcn_rcpf(x0_ * x1_);                    \
    float r23_ = __builtin_amdgcn_rcpf(x2_ * x3_);                    \
    float z01_ = fmaf(WV.y, x0_, WV.x * x1_);                         \
    float z23_ = fmaf(WV.w, x2_, WV.z * x3_);                         \
    ACC = fmaf(r01_, z01_, ACC);                                      \
    ACC = fmaf(r23_, z23_, ACC);                                      \
} while (0)

__global__ __launch_bounds__(256) void k_aff(
    const float* __restrict__ E1g, const float* __restrict__ E2g,
    const float* __restrict__ wo,
    const float* __restrict__ p1g, const float* __restrict__ p2g,
    short* __restrict__ ENb, short* __restrict__ ETb,
    float* __restrict__ S1, float* __restrict__ S2)
{
    const int t  = threadIdx.x;
    const int l0 = blockIdx.x * 32, m0 = blockIdx.y * 32, b = blockIdx.z;

    __shared__ __align__(16) float E2s[32 * 132];   // 16.9 KB (E1 read direct)
    __shared__ __align__(16) float affs[32 * 36];   //  4.6 KB

    const int tl = t >> 4, tm = t & 15;   // cells: l in {tl,tl+16}, m in {tm,tm+16}
    const float* e1a = E1g + (((b << 9) + l0 + tl) << 8);
    const float* e1b = E1g + (((b << 9) + l0 + tl + 16) << 8);
    float acc[2][2] = {};

    for (int kc = 0; kc < 256; kc += 128) {
        #pragma unroll
        for (int i = 0; i < 4; ++i) {               // E2: 32 rows x 128 k
            int slot = i * 256 + t;
            int r = slot >> 5, kq = (slot & 31) << 2;
            *(float4*)(E2s + r * 132 + kq) =
                *(const float4*)(E2g + (((b << 9) + m0 + r) << 8) + kc + kq);
        }
        __syncthreads();
        #pragma unroll 4
        for (int k0 = 0; k0 < 128; k0 += 4) {
            const float4 w  = *(const float4*)(wo + kc + k0);   // uniform -> s_load
            const float4 a0 = *(const float4*)(e1a + kc + k0);  // global direct
            const float4 a1 = *(const float4*)(e1b + kc + k0);
            const float4 q0 = *(const float4*)(E2s + tm * 132 + k0);
            const float4 q1 = *(const float4*)(E2s + (tm + 16) * 132 + k0);
            PAIR(a0, q0, w, acc[0][0]);
            PAIR(a0, q1, w, acc[0][1]);
            PAIR(a1, q0, w, acc[1][0]);
            PAIR(a1, q1, w, acc[1][1]);
        }
        __syncthreads();
    }

    affs[tl * 36 + tm]             = __builtin_amdgcn_exp2f(acc[0][0] * N2LOG2E);
    affs[tl * 36 + tm + 16]        = __builtin_amdgcn_exp2f(acc[0][1] * N2LOG2E);
    affs[(tl + 16) * 36 + tm]      = __builtin_amdgcn_exp2f(acc[1][0] * N2LOG2E);
    affs[(tl + 16) * 36 + tm + 16] = __builtin_amdgcn_exp2f(acc[1][1] * N2LOG2E);
    __syncthreads();

    const int r  = t >> 3;
    const int c4 = (t & 7) << 2;
    // natural (32 l-rows x 32 m-cols): EN[l][m]=E*p1[l] (bf16); S1[l]+=sum_m E*p2[m]
    {
        float4 e = *(const float4*)(affs + r * 36 + c4);
        const float p1r = p1g[(b << 9) + l0 + r];
        short4 sv;
        sv.x = f2bf(e.x * p1r); sv.y = f2bf(e.y * p1r);
        sv.z = f2bf(e.z * p1r); sv.w = f2bf(e.w * p1r);
        *(short4*)(ENb + (((b << 9) + l0 + r) << 9) + m0 + c4) = sv;
        float4 p2v = *(const float4*)(p2g + (b << 9) + m0 + c4);
        float s = (e.x * p2v.x + e.y * p2v.y) + (e.z * p2v.z + e.w * p2v.w);
        s += __shfl_xor(s, 1, 64);
        s += __shfl_xor(s, 2, 64);
        s += __shfl_xor(s, 4, 64);
        if ((t & 7) == 0) atomicAdd(S1 + (b << 9) + l0 + r, s);
    }
    // transposed (32 m-rows x 32 l-cols): ET[m][l]=E^T*p2[m] (bf16); S2[m]+=sum_l E*p1[l]
    {
        float4 te;
        te.x = affs[(c4 + 0) * 36 + r];
        te.y = affs[(c4 + 1) * 36 + r];
        te.z = affs[(c4 + 2) * 36 + r];
        te.w = affs[(c4 + 3) * 36 + r];
        const float p2r = p2g[(b << 9) + m0 + r];
        short4 sv;
        sv.x = f2bf(te.x * p2r); sv.y = f2bf(te.y * p2r);
        sv.z = f2bf(te.z * p2r); sv.w = f2bf(te.w * p2r);
        *(short4*)(ETb + (((b << 9) + m0 + r) << 9) + l0 + c4) = sv;
        float4 p1v = *(const float4*)(p1g + (b << 9) + l0 + c4);
        float s = (te.x * p1v.x + te.y * p1v.y) + (te.z * p1v.z + te.w * p1v.w);
        s += __shfl_xor(s, 1, 64);
        s += __shfl_xor(s, 2, 64);
        s += __shfl_xor(s, 4, 64);
        if ((t & 7) == 0) atomicAdd(S2 + (b << 9) + m0 + r, s);
    }
}

// --------------------------------------------------------------- k_final
// out[row][n] = tanh(P[row][n] + sum_k A_bf[row][k] * (rs[k]*U[k][n])),
// A = ETb (dir0, row=m, k=l) or ENb (dir1, row=l, k=m): [row][k] bf16, stride 512.
__global__ __launch_bounds__(256) void k_final(
    const short* __restrict__ ENb, const short* __restrict__ ETb,
    const float* __restrict__ U1, const float* __restrict__ U2,
    const float* __restrict__ P12, const float* __restrict__ P21,
    const float* __restrict__ S1, const float* __restrict__ S2,
    float* __restrict__ out)
{
    const int t   = threadIdx.x;
    const int r0  = blockIdx.x * 32, n0 = blockIdx.y * 32;
    const int dir = blockIdx.z >> 1, b = blockIdx.z & 1;
    const short* Ag = (dir == 0 ? ETb : ENb) + b * 262144;  // [row][k] bf16
    const float* Sg = (dir == 0 ? S1  : S2)  + b * 512;
    const float* Bg = (dir == 0 ? U1  : U2)  + b * 131072;  // [k][n] f32, stride 256
    const float* Pg = (dir == 0 ? P12 : P21) + b * 131072;  // [row][n], stride 256
    float* o = out + (dir == 0 ? 262144 : 0);

    __shared__ __align__(16) short Bbf[32 * 520];   // [n][k=512] bf16, rs folded
    __shared__ __align__(16) float rs[512];

    for (int i = t; i < 512; i += 256)
        rs[i] = __builtin_amdgcn_rcpf(Sg[i]);
    __syncthreads();

    #pragma unroll
    for (int i = 0; i < 16; ++i) {                  // B: 512 k x 32 n -> [n][k]
        int slot = i * 256 + t;
        int bk = slot >> 3, bn4 = (slot & 7) << 2;
        float4 v = *(const float4*)(Bg + (bk << 8) + n0 + bn4);
        const float r_ = rs[bk];
        Bbf[(bn4 + 0) * 520 + bk] = f2bf(v.x * r_);
        Bbf[(bn4 + 1) * 520 + bk] = f2bf(v.y * r_);
        Bbf[(bn4 + 2) * 520 + bk] = f2bf(v.z * r_);
        Bbf[(bn4 + 3) * 520 + bk] = f2bf(v.w * r_);
    }
    __syncthreads();

    const int w    = t >> 6;
    const int lane = t & 63;
    const int quad = lane >> 4;
    const int lr   = lane & 15;
    const int wr   = (w >> 1) << 4, wc = (w & 1) << 4;
    const short* ap = Ag + (r0 + wr + lr) * 512;    // contiguous bf16 row
    f32x4 acc = {};

    #pragma unroll
    for (int s = 0; s < 16; ++s) {                  // K=512, no barriers
        const int kb = s * 32 + quad * 8;
        bf16x8 a  = *(const bf16x8*)(ap + kb);
        bf16x8 bb = *(const bf16x8*)(Bbf + (wc + lr) * 520 + kb);
        acc = __builtin_amdgcn_mfma_f32_16x16x32_bf16(a, bb, acc, 0, 0, 0);
    }

    const int col = n0 + wc + lr;
    #pragma unroll
    for (int reg = 0; reg < 4; ++reg) {
        const int m = r0 + wr + quad * 4 + reg;
        float v = acc[reg] + Pg[(m << 8) + col];
        float tv = 1.f - 2.f * __builtin_amdgcn_rcpf(
                       __builtin_amdgcn_exp2f(v * TWO_LOG2E) + 1.f);
        o[((m << 1) + b) * 256 + col] = tv;
    }
}

// ---------------------------------------------------------------- launch
extern "C" void kernel_launch(void* const* d_in, const int* in_sizes, int n_in,
                              void* d_out, int out_size, void* d_ws, size_t ws_size,
                              hipStream_t stream)
{
    const float* ctx1 = (const float*)d_in[0];
    const float* ctx2 = (const float*)d_in[1];
    const float* m1   = (const float*)d_in[2];
    const float* m2   = (const float*)d_in[3];
    const float* Wh   = (const float*)d_in[4];
    const float* bh   = (const float*)d_in[5];
    const float* wo   = (const float*)d_in[6];
    const float* W12  = (const float*)d_in[7];
    const float* b12  = (const float*)d_in[8];
    const float* W21  = (const float*)d_in[9];
    const float* b21  = (const float*)d_in[10];
    float* out = (float*)d_out;
    float* ws  = (float*)d_ws;

    float* E1  = ws;                 // 262144
    float* E2  = E1  + 262144;
    float* P12 = E2  + 262144;
    float* U1  = P12 + 262144;
    float* P21 = U1  + 262144;
    float* U2  = P21 + 262144;
    float* p1  = U2  + 262144;       // 1024
    float* p2  = p1  + 1024;
    float* S1  = p2  + 1024;         // 1024
    float* S2  = S1  + 1024;
    short* ENb = (short*)(S2 + 1024);    // 524288 shorts (1 MB)
    short* ETb = ENb + 524288;           // 524288 shorts

    hipLaunchKernelGGL(k_proj, dim3(16, 4, 6), dim3(256), 0, stream,
                       ctx1, ctx2, Wh, bh, W12, b12, W21, b21, m1, m2,
                       E1, E2, P12, U1, P21, U2, p1, p2, S1, S2);
    hipLaunchKernelGGL(k_aff, dim3(16, 16, 2), dim3(256), 0, stream,
                       E1, E2, wo, p1, p2, ENb, ETb, S1, S2);
    hipLaunchKernelGGL(k_final, dim3(16, 8, 4), dim3(256), 0, stream,
                       ENb, ETb, U1, U2, P12, P21, S1, S2, out);
}